// Round 14
// baseline (495.399 us; speedup 1.0000x reference)
//
#include <hip/hip_runtime.h>
#include <hip/hip_bf16.h>

typedef unsigned short u16;
typedef __bf16 bf16x8 __attribute__((ext_vector_type(8)));
typedef float f32x4 __attribute__((ext_vector_type(4)));
typedef float f32x16 __attribute__((ext_vector_type(16)));
typedef short v2s __attribute__((ext_vector_type(2)));

#define NN 20000
#define NE 320000

// ---------------- ws layout (bytes) ----------------
constexpr size_t SZ_W1  = (size_t)18 * 17 * 512 * 2;  // eW1: K 288, N 544 (32x32 swz)
constexpr size_t SZ_W2  = (size_t)34 * 4  * 512 * 2;  // eW2: K 544, N 128
constexpr size_t SZ_WC1 = (size_t)8  * 8  * 512 * 2;  // cW1: K 128, N 256
constexpr size_t SZ_WC2 = (size_t)16 * 1  * 512 * 2;  // cW2: K 256, N 32(3)
constexpr size_t SZ_WN1 = (size_t)8  * 32 * 512 * 2;  // nW1 (16x16 swz)
constexpr size_t SZ_WN2 = (size_t)16 * 8  * 512 * 2;  // nW2
constexpr size_t OFF_W1   = 0;
constexpr size_t OFF_W2   = OFF_W1 + SZ_W1;
constexpr size_t OFF_WC1  = OFF_W2 + SZ_W2;
constexpr size_t OFF_WC2  = OFF_WC1 + SZ_WC1;
constexpr size_t OFF_WN1  = OFF_WC2 + SZ_WC2;
constexpr size_t OFF_WN2  = OFF_WN1 + SZ_WN1;
constexpr size_t OFF_HB   = OFF_WN2 + SZ_WN2;         // bf16 [NN,128]
constexpr size_t SZ_HB    = (size_t)NN * 128 * 2;
constexpr size_t OFF_AGGH = OFF_HB + SZ_HB;           // bf16 [NN,128]
constexpr size_t SZ_AGGH  = (size_t)NN * 128 * 2;
constexpr size_t OFF_AGGC = OFF_AGGH + SZ_AGGH;       // f32 [NN,9]
constexpr size_t SZ_AGGC  = (size_t)NN * 9 * 4;
constexpr size_t OFF_CNT  = OFF_AGGC + SZ_AGGC;       // f32 [NN]
constexpr size_t SZ_CNT   = (size_t)NN * 4;

// native RTNE bf16 convert (1 VALU op vs 4 for bit-twiddled round)
__device__ __forceinline__ u16 f2b(float x) {
  __bf16 b = (__bf16)x;
  return __builtin_bit_cast(u16, b);
}
__device__ __forceinline__ float b2f(unsigned b) {
  union { unsigned u; float f; } v; v.u = b << 16; return v.f;
}
__device__ __forceinline__ float silu_f(float x) {
  float e = __builtin_amdgcn_exp2f(-1.44269504088896f * x);
  return x * __builtin_amdgcn_rcpf(1.f + e);
}
__device__ __forceinline__ void pk_atomic_bf16(u16* p, float a, float b) {
#if __has_builtin(__builtin_amdgcn_global_atomic_fadd_v2bf16)
  v2s v; v[0] = (short)f2b(a); v[1] = (short)f2b(b);
  __builtin_amdgcn_global_atomic_fadd_v2bf16((v2s*)p, v);
#else
  unsigned* q = (unsigned*)p;
  unsigned old = *q, assumed;
  do {
    assumed = old;
    float lo = b2f(assumed & 0xffffu) + a;
    float hi = b2f(assumed >> 16) + b;
    unsigned nv = (unsigned)f2b(lo) | ((unsigned)f2b(hi) << 16);
    old = atomicCAS(q, assumed, nv);
  } while (old != assumed);
#endif
}
__device__ __forceinline__ f32x16 z16() {
  f32x16 v;
  #pragma unroll
  for (int i = 0; i < 16; i++) v[i] = 0.f;
  return v;
}
__device__ __forceinline__ bf16x8 ldf(const u16* p) {
  return *reinterpret_cast<const bf16x8*>(p);
}
#define MFMA32(A,B,C) __builtin_amdgcn_mfma_f32_32x32x16_bf16((A),(B),(C),0,0,0)

// 16x16 B-fragment swizzle (node kernel weights)
__global__ void swz_kernel(const float* __restrict__ W, u16* __restrict__ dst,
                           int Kreal, int Nreal, int KT, int NT) {
  int idx = blockIdx.x * 256 + threadIdx.x;
  int total = KT * NT * 512;
  if (idx >= total) return;
  int e = idx & 7, l = (idx >> 3) & 63, blk = idx >> 9;
  int kt = blk % KT, nt = blk / KT;
  int k = kt * 32 + ((l >> 4) * 8) + e;
  int n = nt * 16 + (l & 15);
  float v = (k < Kreal && n < Nreal) ? W[(size_t)k * Nreal + n] : 0.f;
  dst[idx] = f2b(v);
}

// 32x32 B-fragment swizzle
__global__ void swz32_kernel(const float* __restrict__ W, u16* __restrict__ dst,
                             int Kreal, int Nreal, int KT, int NT) {
  int idx = blockIdx.x * 256 + threadIdx.x;
  int total = KT * NT * 512;
  if (idx >= total) return;
  int e = idx & 7, l = (idx >> 3) & 63, blk = idx >> 9;
  int kt = blk % KT, nt = blk / KT;
  int k = kt * 16 + ((l >> 5) * 8) + e;
  int n = nt * 32 + (l & 31);
  float v = (k < Kreal && n < Nreal) ? W[(size_t)k * Nreal + n] : 0.f;
  dst[idx] = f2b(v);
}

__global__ void tob16_kernel(const float* __restrict__ x, u16* __restrict__ y, int n) {
  int i = blockIdx.x * 256 + threadIdx.x;
  if (i < n) y[i] = f2b(x[i]);
}

// ---- edge pipeline: M=32, 4 waves, 5 blocks/CU, dual accumulator chains ----
__global__ __launch_bounds__(256, 5)
void edge_kernel(const u16* __restrict__ hb, const int* __restrict__ eidx,
                 const float* __restrict__ coord,
                 const u16* __restrict__ W1s, const float* __restrict__ b1,
                 const u16* __restrict__ W2s, const float* __restrict__ b2,
                 const u16* __restrict__ WC1s, const float* __restrict__ bc1,
                 const u16* __restrict__ WC2s,
                 u16* __restrict__ agg_h, float* __restrict__ agg_c,
                 float* __restrict__ cnt) {
  __shared__ __align__(16) u16 bufA[32 * 296];  // A1 [32][288+8] -> Y3 [32][264]
  __shared__ __align__(16) u16 bufB[32 * 136];  // Y1 chunk [32][128+8] -> ef [32][136]
  __shared__ float phi_s[32][4];
  __shared__ int row_s[32];

  const int tid = threadIdx.x;
  const int lane = tid & 63;
  const int nh = tid >> 6;
  const int l5 = lane & 31;
  const int hi = lane >> 5;
  const int e0 = blockIdx.x << 5;

  // gather h (all waves) + radial (tid<32)
  for (int q = tid; q < 1024; q += 256) {
    const int e = q >> 5, sub = q & 31, which = sub >> 4, j = sub & 15;
    const int node = eidx[(which ? NE : 0) + e0 + e];
    const int4 v = *reinterpret_cast<const int4*>(hb + (size_t)node * 128 + j * 8);
    *reinterpret_cast<int4*>(bufA + e * 296 + which * 128 + j * 8) = v;
  }
  if (tid < 32) {
    const int r = eidx[e0 + tid], c = eidx[NE + e0 + tid];
    row_s[tid] = r;
    float cd[9];
    #pragma unroll
    for (int i = 0; i < 9; i++) cd[i] = coord[r * 9 + i] - coord[c * 9 + i];
    u16* arow = bufA + tid * 296;
    #pragma unroll
    for (int a = 0; a < 3; a++)
      #pragma unroll
      for (int b = 0; b < 3; b++) {
        float rad = cd[a*3]*cd[b*3] + cd[a*3+1]*cd[b*3+1] + cd[a*3+2]*cd[b*3+2];
        arow[256 + a * 3 + b] = f2b(rad);
      }
    #pragma unroll
    for (int k = 265; k < 288; k++) arow[k] = (u16)0;
  }
  __syncthreads();  // A1 + row_s ready

  // ---- chunked GEMM1 [32,288]x[288,544] -> silu -> GEMM2 [32,544]x[544,128] ----
  // dual persistent GEMM2 accumulators (even/odd k2) for 2x chain ILP
  f32x16 acc2a = z16(), acc2b = z16();

  #pragma unroll
  for (int c = 0; c < 5; c++) {
    const int nt = c * 4 + nh;
    const bool act = (nt < 17);
    f32x16 a1a = z16(), a1b = z16();   // dual GEMM1 chains (even/odd kt)

    if (act) {
      const u16* wp = W1s + (((nt * 18) << 6) + lane) * 8;
      const u16* ap = bufA + l5 * 296 + hi * 8;
      #pragma unroll
      for (int kt = 0; kt < 18; kt += 2) {
        a1a = MFMA32(ldf(ap + kt * 16), ldf(wp + kt * 512), a1a);
        a1b = MFMA32(ldf(ap + (kt + 1) * 16), ldf(wp + (kt + 1) * 512), a1b);
      }
    }
    __syncthreads();  // prev chunk's GEMM2 reads of bufB complete
    if (act) {
      const int colg = nt * 32 + l5;
      const float bias = (colg < 530) ? b1[colg] : 0.f;
      const int coll = nh * 32 + l5;
      #pragma unroll
      for (int r = 0; r < 16; r++) {
        const int rowi = (r & 3) + 8 * (r >> 2) + 4 * hi;
        bufB[rowi * 136 + coll] = f2b(silu_f(a1a[r] + a1b[r] + bias));
      }
    }
    __syncthreads();  // Y1 chunk ready

    const u16* bp = bufB + l5 * 136 + hi * 8;
    const int nk2 = (c < 4) ? 8 : 2;
    const u16* wp2 = W2s + (((nh * 34 + c * 8) << 6) + lane) * 8;
    for (int k2 = 0; k2 < nk2; k2 += 2) {
      acc2a = MFMA32(ldf(bp + k2 * 16), ldf(wp2 + k2 * 512), acc2a);
      acc2b = MFMA32(ldf(bp + (k2 + 1) * 16), ldf(wp2 + (k2 + 1) * 512), acc2b);
    }
  }
  __syncthreads();  // all GEMM2 reads of bufB done

  // ef = silu(acc2a+acc2b + b2): keep in regs, write bf16 to bufB [32][136]
  f32x16 efv;
  {
    const int col = nh * 32 + l5;
    const float bias = b2[col];
    #pragma unroll
    for (int r = 0; r < 16; r++) {
      const int rowi = (r & 3) + 8 * (r >> 2) + 4 * hi;
      efv[r] = silu_f(acc2a[r] + acc2b[r] + bias);
      bufB[rowi * 136 + col] = f2b(efv[r]);
    }
  }
  __syncthreads();  // ef ready

  // GEMM3: ef[32,128] x WC1[128,256]; two accs already = two chains
  f32x16 acc3[2];
  #pragma unroll
  for (int i = 0; i < 2; i++) acc3[i] = z16();
  {
    const u16* wpa = WC1s + ((((nh * 2) * 8) << 6) + lane) * 8;
    const u16* wpb = wpa + 8 * 512;
    const u16* bp = bufB + l5 * 136 + hi * 8;
    #pragma unroll
    for (int kt = 0; kt < 8; kt++) {
      const bf16x8 a = ldf(bp + kt * 16);
      acc3[0] = MFMA32(a, ldf(wpa + kt * 512), acc3[0]);
      acc3[1] = MFMA32(a, ldf(wpb + kt * 512), acc3[1]);
    }
  }

  // agg_h packed-bf16 atomics (drain hides under epi3)
  {
    const int col = nh * 32 + l5;
    #pragma unroll
    for (int r = 0; r < 16; r++) {
      const float other = __shfl_xor(efv[r], 1);
      if ((l5 & 1) == 0) {
        const int rowi = (r & 3) + 8 * (r >> 2) + 4 * hi;
        pk_atomic_bf16(agg_h + (size_t)row_s[rowi] * 128 + col, efv[r], other);
      }
    }
  }

  // epi3 -> bufA as Y3 [32][264]
  #pragma unroll
  for (int i = 0; i < 2; i++) {
    const int col = (nh * 2 + i) * 32 + l5;
    const float bias = bc1[col];
    #pragma unroll
    for (int r = 0; r < 16; r++) {
      const int rowi = (r & 3) + 8 * (r >> 2) + 4 * hi;
      bufA[rowi * 264 + col] = f2b(silu_f(acc3[i][r] + bias));
    }
  }
  __syncthreads();  // Y3 ready

  // GEMM4 (wave 0 only): Y3[32,256] x WC2[256,32(3)], dual chains
  if (nh == 0) {
    f32x16 a4a = z16(), a4b = z16();
    const u16* wp4 = WC2s + lane * 8;
    const u16* ap = bufA + l5 * 264 + hi * 8;
    #pragma unroll
    for (int kt = 0; kt < 16; kt += 2) {
      a4a = MFMA32(ldf(ap + kt * 16), ldf(wp4 + kt * 512), a4a);
      a4b = MFMA32(ldf(ap + (kt + 1) * 16), ldf(wp4 + (kt + 1) * 512), a4b);
    }
    if (l5 < 3) {
      #pragma unroll
      for (int r = 0; r < 16; r++)
        phi_s[(r & 3) + 8 * (r >> 2) + 4 * hi][l5] = a4a[r] + a4b[r];
    }
    // wave-internal LDS handoff (compiler inserts lgkmcnt wait)
    if (lane < 32) {
      const int r = row_s[lane], ci = eidx[NE + e0 + lane];
      float cd[9];
      #pragma unroll
      for (int i = 0; i < 9; i++) cd[i] = coord[r * 9 + i] - coord[ci * 9 + i];
      const float p0 = phi_s[lane][0], p1 = phi_s[lane][1], p2 = phi_s[lane][2];
      float* gc = agg_c + (size_t)r * 9;
      #pragma unroll
      for (int d = 0; d < 3; d++) {
        atomicAdd(gc + d,     cd[d]     * p0);
        atomicAdd(gc + 3 + d, cd[3 + d] * p1);
        atomicAdd(gc + 6 + d, cd[6 + d] * p2);
      }
      atomicAdd(cnt + r, 1.f);
    }
  }
}

// ---------------- node MLP (16x16 path; agg_h bf16) ----------------
__global__ __launch_bounds__(512)
void node_kernel(const float* __restrict__ h, const u16* __restrict__ hb,
                 const u16* __restrict__ aggh,
                 const u16* __restrict__ WN1s, const float* __restrict__ nb1,
                 const u16* __restrict__ WN2s, const float* __restrict__ nb2,
                 float* __restrict__ out) {
  __shared__ __align__(16) u16 buf[64 * 520];
  const int tid = threadIdx.x;
  const int lane = tid & 63;
  const int w = tid >> 6;
  const int l_lo = lane & 15;
  const int l_hi = lane >> 4;
  const int n0 = blockIdx.x << 6;

  for (int q = tid; q < 2048; q += 512) {
    const int e = q >> 5, sub = q & 31, which = sub >> 4, j = sub & 15;
    const int row = n0 + e;
    const u16* src = which ? aggh : hb;
    int4 v;
    if (row < NN) v = *reinterpret_cast<const int4*>(src + (size_t)row * 128 + j * 8);
    else { v.x = v.y = v.z = v.w = 0; }
    *reinterpret_cast<int4*>(buf + e * 264 + which * 128 + j * 8) = v;
  }
  __syncthreads();

  f32x4 acc[4][4];
  #pragma unroll
  for (int i = 0; i < 4; i++)
    #pragma unroll
    for (int m = 0; m < 4; m++) acc[i][m] = {0.f, 0.f, 0.f, 0.f};
  for (int kt = 0; kt < 8; kt++) {
    bf16x8 af[4];
    #pragma unroll
    for (int m = 0; m < 4; m++)
      af[m] = *reinterpret_cast<const bf16x8*>(buf + (m * 16 + l_lo) * 264 + kt * 32 + l_hi * 8);
    #pragma unroll
    for (int i = 0; i < 4; i++) {
      const int nt = w + 8 * i;
      const bf16x8 bfr = *reinterpret_cast<const bf16x8*>(WN1s + (((nt * 8 + kt) << 6) + lane) * 8);
      #pragma unroll
      for (int m = 0; m < 4; m++)
        acc[i][m] = __builtin_amdgcn_mfma_f32_16x16x32_bf16(af[m], bfr, acc[i][m], 0, 0, 0);
    }
  }
  __syncthreads();
  #pragma unroll
  for (int i = 0; i < 4; i++) {
    const int nt = w + 8 * i;
    const int coln = nt * 16 + l_lo;
    const float bias = nb1[coln];
    #pragma unroll
    for (int m = 0; m < 4; m++)
      #pragma unroll
      for (int rr = 0; rr < 4; rr++) {
        const int row = m * 16 + l_hi * 4 + rr;
        buf[row * 520 + coln] = f2b(silu_f(acc[i][m][rr] + bias));
      }
  }
  __syncthreads();

  f32x4 acc2[4];
  #pragma unroll
  for (int m = 0; m < 4; m++) acc2[m] = {0.f, 0.f, 0.f, 0.f};
  for (int kt = 0; kt < 16; kt++) {
    const bf16x8 bfr = *reinterpret_cast<const bf16x8*>(WN2s + (((w * 16 + kt) << 6) + lane) * 8);
    #pragma unroll
    for (int m = 0; m < 4; m++) {
      const bf16x8 af = *reinterpret_cast<const bf16x8*>(buf + (m * 16 + l_lo) * 520 + kt * 32 + l_hi * 8);
      acc2[m] = __builtin_amdgcn_mfma_f32_16x16x32_bf16(af, bfr, acc2[m], 0, 0, 0);
    }
  }
  {
    const int coln = w * 16 + l_lo;
    const float bias = nb2[coln];
    #pragma unroll
    for (int m = 0; m < 4; m++)
      #pragma unroll
      for (int rr = 0; rr < 4; rr++) {
        const int row = n0 + m * 16 + l_hi * 4 + rr;
        if (row < NN)
          out[(size_t)row * 128 + coln] = h[(size_t)row * 128 + coln] + silu_f(acc2[m][rr] + bias);
      }
  }
}

__global__ void coord_kernel(const float* __restrict__ coord, const float* __restrict__ agg_c,
                             const float* __restrict__ cnt, float* __restrict__ out) {
  int i = blockIdx.x * 256 + threadIdx.x;
  if (i < NN * 9) {
    float cc = fmaxf(cnt[i / 9], 1.f);
    float v = agg_c[i] / cc;
    v = fminf(fmaxf(v, -10.f), 10.f);
    out[i] = coord[i] + v;
  }
}

extern "C" void kernel_launch(void* const* d_in, const int* in_sizes, int n_in,
                              void* d_out, int out_size, void* d_ws, size_t ws_size,
                              hipStream_t stream) {
  (void)in_sizes; (void)n_in; (void)out_size; (void)ws_size;
  const float* h     = (const float*)d_in[0];
  const int*   eidx  = (const int*)d_in[1];
  const float* coord = (const float*)d_in[2];
  const float* eW1 = (const float*)d_in[3];  const float* eb1 = (const float*)d_in[4];
  const float* eW2 = (const float*)d_in[5];  const float* eb2 = (const float*)d_in[6];
  const float* nW1 = (const float*)d_in[7];  const float* nb1 = (const float*)d_in[8];
  const float* nW2 = (const float*)d_in[9];  const float* nb2 = (const float*)d_in[10];
  const float* cW1 = (const float*)d_in[11]; const float* cb1 = (const float*)d_in[12];
  const float* cW2 = (const float*)d_in[13];

  char* ws = (char*)d_ws;
  u16* W1s  = (u16*)(ws + OFF_W1);
  u16* W2s  = (u16*)(ws + OFF_W2);
  u16* WC1s = (u16*)(ws + OFF_WC1);
  u16* WC2s = (u16*)(ws + OFF_WC2);
  u16* WN1s = (u16*)(ws + OFF_WN1);
  u16* WN2s = (u16*)(ws + OFF_WN2);
  u16* hb   = (u16*)(ws + OFF_HB);
  u16* agg_h  = (u16*)(ws + OFF_AGGH);
  float* agg_c = (float*)(ws + OFF_AGGC);
  float* cnt   = (float*)(ws + OFF_CNT);
  float* out   = (float*)d_out;

  hipMemsetAsync(ws + OFF_AGGH, 0, SZ_AGGH + SZ_AGGC + SZ_CNT, stream);

  swz32_kernel<<<18 * 17 * 2, 256, 0, stream>>>(eW1, W1s, 265, 530, 18, 17);
  swz32_kernel<<<34 * 4 * 2, 256, 0, stream>>>(eW2, W2s, 530, 128, 34, 4);
  swz32_kernel<<<8 * 8 * 2, 256, 0, stream>>>(cW1, WC1s, 128, 256, 8, 8);
  swz32_kernel<<<16 * 1 * 2, 256, 0, stream>>>(cW2, WC2s, 256, 3, 16, 1);
  swz_kernel<<<8 * 32 * 2, 256, 0, stream>>>(nW1, WN1s, 256, 512, 8, 32);
  swz_kernel<<<16 * 8 * 2, 256, 0, stream>>>(nW2, WN2s, 512, 128, 16, 8);
  tob16_kernel<<<(NN * 128 + 255) / 256, 256, 0, stream>>>(h, hb, NN * 128);

  edge_kernel<<<NE / 32, 256, 0, stream>>>(hb, eidx, coord, W1s, eb1, W2s, eb2,
                                           WC1s, cb1, WC2s, agg_h, agg_c, cnt);
  node_kernel<<<(NN + 63) / 64, 512, 0, stream>>>(h, hb, agg_h, WN1s, nb1, WN2s, nb2, out);
  coord_kernel<<<(NN * 9 + 255) / 256, 256, 0, stream>>>(coord, agg_c, cnt, out + (size_t)NN * 128);
}

// Round 15
// 387.990 us; speedup vs baseline: 1.2768x; 1.2768x over previous
//
#include <hip/hip_runtime.h>
#include <hip/hip_bf16.h>

typedef unsigned short u16;
typedef __bf16 bf16x8 __attribute__((ext_vector_type(8)));
typedef float f32x4 __attribute__((ext_vector_type(4)));
typedef float f32x16 __attribute__((ext_vector_type(16)));
typedef short v2s __attribute__((ext_vector_type(2)));

#define NN 20000
#define NE 320000

// ---------------- ws layout (bytes) ----------------
constexpr size_t SZ_W1  = (size_t)18 * 17 * 512 * 2;  // eW1: K 288, N 544 (32x32 swz)
constexpr size_t SZ_W2  = (size_t)34 * 4  * 512 * 2;  // eW2: K 544, N 128
constexpr size_t SZ_WC1 = (size_t)8  * 8  * 512 * 2;  // cW1: K 128, N 256
constexpr size_t SZ_WC2 = (size_t)16 * 1  * 512 * 2;  // cW2: K 256, N 32(3)
constexpr size_t SZ_WN1 = (size_t)8  * 32 * 512 * 2;  // nW1 (16x16 swz)
constexpr size_t SZ_WN2 = (size_t)16 * 8  * 512 * 2;  // nW2
constexpr size_t OFF_W1   = 0;
constexpr size_t OFF_W2   = OFF_W1 + SZ_W1;
constexpr size_t OFF_WC1  = OFF_W2 + SZ_W2;
constexpr size_t OFF_WC2  = OFF_WC1 + SZ_WC1;
constexpr size_t OFF_WN1  = OFF_WC2 + SZ_WC2;
constexpr size_t OFF_WN2  = OFF_WN1 + SZ_WN1;
constexpr size_t OFF_HB   = OFF_WN2 + SZ_WN2;         // bf16 [NN,128]
constexpr size_t SZ_HB    = (size_t)NN * 128 * 2;
constexpr size_t OFF_AGGH = OFF_HB + SZ_HB;           // bf16 [NN,128]
constexpr size_t SZ_AGGH  = (size_t)NN * 128 * 2;
constexpr size_t OFF_AGGC = OFF_AGGH + SZ_AGGH;       // f32 [NN,9]
constexpr size_t SZ_AGGC  = (size_t)NN * 9 * 4;
constexpr size_t OFF_CNT  = OFF_AGGC + SZ_AGGC;       // f32 [NN]
constexpr size_t SZ_CNT   = (size_t)NN * 4;

// native RTNE bf16 convert (1 VALU op)
__device__ __forceinline__ u16 f2b(float x) {
  __bf16 b = (__bf16)x;
  return __builtin_bit_cast(u16, b);
}
__device__ __forceinline__ float b2f(unsigned b) {
  union { unsigned u; float f; } v; v.u = b << 16; return v.f;
}
__device__ __forceinline__ float silu_f(float x) {
  float e = __builtin_amdgcn_exp2f(-1.44269504088896f * x);
  return x * __builtin_amdgcn_rcpf(1.f + e);
}
__device__ __forceinline__ void pk_atomic_bf16(u16* p, float a, float b) {
#if __has_builtin(__builtin_amdgcn_global_atomic_fadd_v2bf16)
  v2s v; v[0] = (short)f2b(a); v[1] = (short)f2b(b);
  __builtin_amdgcn_global_atomic_fadd_v2bf16((v2s*)p, v);
#else
  unsigned* q = (unsigned*)p;
  unsigned old = *q, assumed;
  do {
    assumed = old;
    float lo = b2f(assumed & 0xffffu) + a;
    float hi = b2f(assumed >> 16) + b;
    unsigned nv = (unsigned)f2b(lo) | ((unsigned)f2b(hi) << 16);
    old = atomicCAS(q, assumed, nv);
  } while (old != assumed);
#endif
}
__device__ __forceinline__ f32x16 z16() {
  f32x16 v;
  #pragma unroll
  for (int i = 0; i < 16; i++) v[i] = 0.f;
  return v;
}
__device__ __forceinline__ bf16x8 ldf(const u16* p) {
  return *reinterpret_cast<const bf16x8*>(p);
}
#define MFMA32(A,B,C) __builtin_amdgcn_mfma_f32_32x32x16_bf16((A),(B),(C),0,0,0)

// 16x16 B-fragment swizzle (node kernel weights)
__global__ void swz_kernel(const float* __restrict__ W, u16* __restrict__ dst,
                           int Kreal, int Nreal, int KT, int NT) {
  int idx = blockIdx.x * 256 + threadIdx.x;
  int total = KT * NT * 512;
  if (idx >= total) return;
  int e = idx & 7, l = (idx >> 3) & 63, blk = idx >> 9;
  int kt = blk % KT, nt = blk / KT;
  int k = kt * 32 + ((l >> 4) * 8) + e;
  int n = nt * 16 + (l & 15);
  float v = (k < Kreal && n < Nreal) ? W[(size_t)k * Nreal + n] : 0.f;
  dst[idx] = f2b(v);
}

// 32x32 B-fragment swizzle
__global__ void swz32_kernel(const float* __restrict__ W, u16* __restrict__ dst,
                             int Kreal, int Nreal, int KT, int NT) {
  int idx = blockIdx.x * 256 + threadIdx.x;
  int total = KT * NT * 512;
  if (idx >= total) return;
  int e = idx & 7, l = (idx >> 3) & 63, blk = idx >> 9;
  int kt = blk % KT, nt = blk / KT;
  int k = kt * 16 + ((l >> 5) * 8) + e;
  int n = nt * 32 + (l & 31);
  float v = (k < Kreal && n < Nreal) ? W[(size_t)k * Nreal + n] : 0.f;
  dst[idx] = f2b(v);
}

__global__ void tob16_kernel(const float* __restrict__ x, u16* __restrict__ y, int n) {
  int i = blockIdx.x * 256 + threadIdx.x;
  if (i < n) y[i] = f2b(x[i]);
}

// ---- edge pipeline: M=32, 4 waves, 5 blocks/CU, transient dual chains ----
__global__ __launch_bounds__(256, 5)
void edge_kernel(const u16* __restrict__ hb, const int* __restrict__ eidx,
                 const float* __restrict__ coord,
                 const u16* __restrict__ W1s, const float* __restrict__ b1,
                 const u16* __restrict__ W2s, const float* __restrict__ b2,
                 const u16* __restrict__ WC1s, const float* __restrict__ bc1,
                 const u16* __restrict__ WC2s,
                 u16* __restrict__ agg_h, float* __restrict__ agg_c,
                 float* __restrict__ cnt) {
  __shared__ __align__(16) u16 bufA[32 * 296];  // A1 [32][288+8] -> Y3 [32][264]
  __shared__ __align__(16) u16 bufB[32 * 136];  // Y1 chunk [32][128+8] -> ef [32][136]
  __shared__ float phi_s[32][4];
  __shared__ int row_s[32];

  const int tid = threadIdx.x;
  const int lane = tid & 63;
  const int nh = tid >> 6;
  const int l5 = lane & 31;
  const int hi = lane >> 5;
  const int e0 = blockIdx.x << 5;

  // gather h (all waves) + radial (tid<32)
  for (int q = tid; q < 1024; q += 256) {
    const int e = q >> 5, sub = q & 31, which = sub >> 4, j = sub & 15;
    const int node = eidx[(which ? NE : 0) + e0 + e];
    const int4 v = *reinterpret_cast<const int4*>(hb + (size_t)node * 128 + j * 8);
    *reinterpret_cast<int4*>(bufA + e * 296 + which * 128 + j * 8) = v;
  }
  if (tid < 32) {
    const int r = eidx[e0 + tid], c = eidx[NE + e0 + tid];
    row_s[tid] = r;
    float cd[9];
    #pragma unroll
    for (int i = 0; i < 9; i++) cd[i] = coord[r * 9 + i] - coord[c * 9 + i];
    u16* arow = bufA + tid * 296;
    #pragma unroll
    for (int a = 0; a < 3; a++)
      #pragma unroll
      for (int b = 0; b < 3; b++) {
        float rad = cd[a*3]*cd[b*3] + cd[a*3+1]*cd[b*3+1] + cd[a*3+2]*cd[b*3+2];
        arow[256 + a * 3 + b] = f2b(rad);
      }
    #pragma unroll
    for (int k = 265; k < 288; k++) arow[k] = (u16)0;
  }
  __syncthreads();  // A1 + row_s ready

  // ---- chunked GEMM1 [32,288]x[288,544] -> silu -> GEMM2 [32,544]x[544,128] ----
  // single persistent acc2; GEMM1 uses two TRANSIENT chains (even/odd kt)
  f32x16 acc2 = z16();

  for (int c = 0; c < 5; c++) {
    const int nt = c * 4 + nh;
    const bool act = (nt < 17);
    f32x16 a1a = z16(), a1b = z16();

    if (act) {
      const u16* wp = W1s + (((nt * 18) << 6) + lane) * 8;
      const u16* ap = bufA + l5 * 296 + hi * 8;
      #pragma unroll
      for (int kt = 0; kt < 18; kt += 2) {
        a1a = MFMA32(ldf(ap + kt * 16), ldf(wp + kt * 512), a1a);
        a1b = MFMA32(ldf(ap + (kt + 1) * 16), ldf(wp + (kt + 1) * 512), a1b);
      }
    }
    __syncthreads();  // prev chunk's GEMM2 reads of bufB complete
    if (act) {
      const int colg = nt * 32 + l5;
      const float bias = (colg < 530) ? b1[colg] : 0.f;
      const int coll = nh * 32 + l5;
      #pragma unroll
      for (int r = 0; r < 16; r++) {
        const int rowi = (r & 3) + 8 * (r >> 2) + 4 * hi;
        bufB[rowi * 136 + coll] = f2b(silu_f(a1a[r] + a1b[r] + bias));
      }
    }
    __syncthreads();  // Y1 chunk ready

    const u16* bp = bufB + l5 * 136 + hi * 8;
    const int nk2 = (c < 4) ? 8 : 2;
    const u16* wp2 = W2s + (((nh * 34 + c * 8) << 6) + lane) * 8;
    for (int k2 = 0; k2 < nk2; k2++)
      acc2 = MFMA32(ldf(bp + k2 * 16), ldf(wp2 + k2 * 512), acc2);
  }
  __syncthreads();  // all GEMM2 reads of bufB done

  // ef = silu(acc2 + b2): keep in regs, write bf16 to bufB [32][136]
  f32x16 efv;
  {
    const int col = nh * 32 + l5;
    const float bias = b2[col];
    #pragma unroll
    for (int r = 0; r < 16; r++) {
      const int rowi = (r & 3) + 8 * (r >> 2) + 4 * hi;
      efv[r] = silu_f(acc2[r] + bias);
      bufB[rowi * 136 + col] = f2b(efv[r]);
    }
  }
  __syncthreads();  // ef ready

  // GEMM3: ef[32,128] x WC1[128,256]; two accs = two chains already
  f32x16 acc3[2];
  #pragma unroll
  for (int i = 0; i < 2; i++) acc3[i] = z16();
  {
    const u16* wpa = WC1s + ((((nh * 2) * 8) << 6) + lane) * 8;
    const u16* wpb = wpa + 8 * 512;
    const u16* bp = bufB + l5 * 136 + hi * 8;
    #pragma unroll
    for (int kt = 0; kt < 8; kt++) {
      const bf16x8 a = ldf(bp + kt * 16);
      acc3[0] = MFMA32(a, ldf(wpa + kt * 512), acc3[0]);
      acc3[1] = MFMA32(a, ldf(wpb + kt * 512), acc3[1]);
    }
  }

  // agg_h packed-bf16 atomics (drain hides under epi3)
  {
    const int col = nh * 32 + l5;
    #pragma unroll
    for (int r = 0; r < 16; r++) {
      const float other = __shfl_xor(efv[r], 1);
      if ((l5 & 1) == 0) {
        const int rowi = (r & 3) + 8 * (r >> 2) + 4 * hi;
        pk_atomic_bf16(agg_h + (size_t)row_s[rowi] * 128 + col, efv[r], other);
      }
    }
  }

  // epi3 -> bufA as Y3 [32][264]
  #pragma unroll
  for (int i = 0; i < 2; i++) {
    const int col = (nh * 2 + i) * 32 + l5;
    const float bias = bc1[col];
    #pragma unroll
    for (int r = 0; r < 16; r++) {
      const int rowi = (r & 3) + 8 * (r >> 2) + 4 * hi;
      bufA[rowi * 264 + col] = f2b(silu_f(acc3[i][r] + bias));
    }
  }
  __syncthreads();  // Y3 ready

  // GEMM4 (wave 0 only): Y3[32,256] x WC2[256,32(3)], transient dual chains
  if (nh == 0) {
    f32x16 a4a = z16(), a4b = z16();
    const u16* wp4 = WC2s + lane * 8;
    const u16* ap = bufA + l5 * 264 + hi * 8;
    #pragma unroll
    for (int kt = 0; kt < 16; kt += 2) {
      a4a = MFMA32(ldf(ap + kt * 16), ldf(wp4 + kt * 512), a4a);
      a4b = MFMA32(ldf(ap + (kt + 1) * 16), ldf(wp4 + (kt + 1) * 512), a4b);
    }
    if (l5 < 3) {
      #pragma unroll
      for (int r = 0; r < 16; r++)
        phi_s[(r & 3) + 8 * (r >> 2) + 4 * hi][l5] = a4a[r] + a4b[r];
    }
    // wave-internal LDS handoff (compiler inserts lgkmcnt wait)
    if (lane < 32) {
      const int r = row_s[lane], ci = eidx[NE + e0 + lane];
      float cd[9];
      #pragma unroll
      for (int i = 0; i < 9; i++) cd[i] = coord[r * 9 + i] - coord[ci * 9 + i];
      const float p0 = phi_s[lane][0], p1 = phi_s[lane][1], p2 = phi_s[lane][2];
      float* gc = agg_c + (size_t)r * 9;
      #pragma unroll
      for (int d = 0; d < 3; d++) {
        atomicAdd(gc + d,     cd[d]     * p0);
        atomicAdd(gc + 3 + d, cd[3 + d] * p1);
        atomicAdd(gc + 6 + d, cd[6 + d] * p2);
      }
      atomicAdd(cnt + r, 1.f);
    }
  }
}

// ---------------- node MLP (16x16 path; agg_h bf16) ----------------
__global__ __launch_bounds__(512)
void node_kernel(const float* __restrict__ h, const u16* __restrict__ hb,
                 const u16* __restrict__ aggh,
                 const u16* __restrict__ WN1s, const float* __restrict__ nb1,
                 const u16* __restrict__ WN2s, const float* __restrict__ nb2,
                 float* __restrict__ out) {
  __shared__ __align__(16) u16 buf[64 * 520];
  const int tid = threadIdx.x;
  const int lane = tid & 63;
  const int w = tid >> 6;
  const int l_lo = lane & 15;
  const int l_hi = lane >> 4;
  const int n0 = blockIdx.x << 6;

  for (int q = tid; q < 2048; q += 512) {
    const int e = q >> 5, sub = q & 31, which = sub >> 4, j = sub & 15;
    const int row = n0 + e;
    const u16* src = which ? aggh : hb;
    int4 v;
    if (row < NN) v = *reinterpret_cast<const int4*>(src + (size_t)row * 128 + j * 8);
    else { v.x = v.y = v.z = v.w = 0; }
    *reinterpret_cast<int4*>(buf + e * 264 + which * 128 + j * 8) = v;
  }
  __syncthreads();

  f32x4 acc[4][4];
  #pragma unroll
  for (int i = 0; i < 4; i++)
    #pragma unroll
    for (int m = 0; m < 4; m++) acc[i][m] = {0.f, 0.f, 0.f, 0.f};
  for (int kt = 0; kt < 8; kt++) {
    bf16x8 af[4];
    #pragma unroll
    for (int m = 0; m < 4; m++)
      af[m] = *reinterpret_cast<const bf16x8*>(buf + (m * 16 + l_lo) * 264 + kt * 32 + l_hi * 8);
    #pragma unroll
    for (int i = 0; i < 4; i++) {
      const int nt = w + 8 * i;
      const bf16x8 bfr = *reinterpret_cast<const bf16x8*>(WN1s + (((nt * 8 + kt) << 6) + lane) * 8);
      #pragma unroll
      for (int m = 0; m < 4; m++)
        acc[i][m] = __builtin_amdgcn_mfma_f32_16x16x32_bf16(af[m], bfr, acc[i][m], 0, 0, 0);
    }
  }
  __syncthreads();
  #pragma unroll
  for (int i = 0; i < 4; i++) {
    const int nt = w + 8 * i;
    const int coln = nt * 16 + l_lo;
    const float bias = nb1[coln];
    #pragma unroll
    for (int m = 0; m < 4; m++)
      #pragma unroll
      for (int rr = 0; rr < 4; rr++) {
        const int row = m * 16 + l_hi * 4 + rr;
        buf[row * 520 + coln] = f2b(silu_f(acc[i][m][rr] + bias));
      }
  }
  __syncthreads();

  f32x4 acc2[4];
  #pragma unroll
  for (int m = 0; m < 4; m++) acc2[m] = {0.f, 0.f, 0.f, 0.f};
  for (int kt = 0; kt < 16; kt++) {
    const bf16x8 bfr = *reinterpret_cast<const bf16x8*>(WN2s + (((w * 16 + kt) << 6) + lane) * 8);
    #pragma unroll
    for (int m = 0; m < 4; m++) {
      const bf16x8 af = *reinterpret_cast<const bf16x8*>(buf + (m * 16 + l_lo) * 520 + kt * 32 + l_hi * 8);
      acc2[m] = __builtin_amdgcn_mfma_f32_16x16x32_bf16(af, bfr, acc2[m], 0, 0, 0);
    }
  }
  {
    const int coln = w * 16 + l_lo;
    const float bias = nb2[coln];
    #pragma unroll
    for (int m = 0; m < 4; m++)
      #pragma unroll
      for (int rr = 0; rr < 4; rr++) {
        const int row = n0 + m * 16 + l_hi * 4 + rr;
        if (row < NN)
          out[(size_t)row * 128 + coln] = h[(size_t)row * 128 + coln] + silu_f(acc2[m][rr] + bias);
      }
  }
}

__global__ void coord_kernel(const float* __restrict__ coord, const float* __restrict__ agg_c,
                             const float* __restrict__ cnt, float* __restrict__ out) {
  int i = blockIdx.x * 256 + threadIdx.x;
  if (i < NN * 9) {
    float cc = fmaxf(cnt[i / 9], 1.f);
    float v = agg_c[i] / cc;
    v = fminf(fmaxf(v, -10.f), 10.f);
    out[i] = coord[i] + v;
  }
}

extern "C" void kernel_launch(void* const* d_in, const int* in_sizes, int n_in,
                              void* d_out, int out_size, void* d_ws, size_t ws_size,
                              hipStream_t stream) {
  (void)in_sizes; (void)n_in; (void)out_size; (void)ws_size;
  const float* h     = (const float*)d_in[0];
  const int*   eidx  = (const int*)d_in[1];
  const float* coord = (const float*)d_in[2];
  const float* eW1 = (const float*)d_in[3];  const float* eb1 = (const float*)d_in[4];
  const float* eW2 = (const float*)d_in[5];  const float* eb2 = (const float*)d_in[6];
  const float* nW1 = (const float*)d_in[7];  const float* nb1 = (const float*)d_in[8];
  const float* nW2 = (const float*)d_in[9];  const float* nb2 = (const float*)d_in[10];
  const float* cW1 = (const float*)d_in[11]; const float* cb1 = (const float*)d_in[12];
  const float* cW2 = (const float*)d_in[13];

  char* ws = (char*)d_ws;
  u16* W1s  = (u16*)(ws + OFF_W1);
  u16* W2s  = (u16*)(ws + OFF_W2);
  u16* WC1s = (u16*)(ws + OFF_WC1);
  u16* WC2s = (u16*)(ws + OFF_WC2);
  u16* WN1s = (u16*)(ws + OFF_WN1);
  u16* WN2s = (u16*)(ws + OFF_WN2);
  u16* hb   = (u16*)(ws + OFF_HB);
  u16* agg_h  = (u16*)(ws + OFF_AGGH);
  float* agg_c = (float*)(ws + OFF_AGGC);
  float* cnt   = (float*)(ws + OFF_CNT);
  float* out   = (float*)d_out;

  hipMemsetAsync(ws + OFF_AGGH, 0, SZ_AGGH + SZ_AGGC + SZ_CNT, stream);

  swz32_kernel<<<18 * 17 * 2, 256, 0, stream>>>(eW1, W1s, 265, 530, 18, 17);
  swz32_kernel<<<34 * 4 * 2, 256, 0, stream>>>(eW2, W2s, 530, 128, 34, 4);
  swz32_kernel<<<8 * 8 * 2, 256, 0, stream>>>(cW1, WC1s, 128, 256, 8, 8);
  swz32_kernel<<<16 * 1 * 2, 256, 0, stream>>>(cW2, WC2s, 256, 3, 16, 1);
  swz_kernel<<<8 * 32 * 2, 256, 0, stream>>>(nW1, WN1s, 256, 512, 8, 32);
  swz_kernel<<<16 * 8 * 2, 256, 0, stream>>>(nW2, WN2s, 512, 128, 16, 8);
  tob16_kernel<<<(NN * 128 + 255) / 256, 256, 0, stream>>>(h, hb, NN * 128);

  edge_kernel<<<NE / 32, 256, 0, stream>>>(hb, eidx, coord, W1s, eb1, W2s, eb2,
                                           WC1s, cb1, WC2s, agg_h, agg_c, cnt);
  node_kernel<<<(NN + 63) / 64, 512, 0, stream>>>(h, hb, agg_h, WN1s, nb1, WN2s, nb2, out);
  coord_kernel<<<(NN * 9 + 255) / 256, 256, 0, stream>>>(coord, agg_c, cnt, out + (size_t)NN * 128);
}